// Round 6
// baseline (130.037 us; speedup 1.0000x reference)
//
#include <hip/hip_runtime.h>

#define C_CH 128
#define I_CH 16
#define NVOX 9216   // 16*24*24
#define BATCH 2
#define LOG2E 1.44269504088896340736f

typedef unsigned short ushort_t;
typedef unsigned int uint_t;
typedef short bf16x8 __attribute__((ext_vector_type(8)));
typedef float f32x4 __attribute__((ext_vector_type(4)));

static __device__ inline ushort_t f2bf_rne(float x) {
    uint_t u = __builtin_bit_cast(uint_t, x);
    u = (u + 0x7FFFu + ((u >> 16) & 1u)) >> 16;
    return (ushort_t)u;
}

static __device__ inline float fast_exp2(float x) {
#if __has_builtin(__builtin_amdgcn_exp2f)
    return __builtin_amdgcn_exp2f(x);
#else
    return exp2f(x);
#endif
}

// ---------------------------------------------------------------------------
// Kernel 1: QKV projection -> bf16 (q pre-scaled by log2e).
// W staged in LDS (24 KB, uniform-broadcast b128 reads); x tile in LDS.
//   qb[vox][16], kb[vox][16]  (voxel-major), vT[b][i][NVOX] (i-major)
// ---------------------------------------------------------------------------
__global__ __launch_bounds__(256) void qkv_kernel(
    const float* __restrict__ x,
    const float* __restrict__ Wq, const float* __restrict__ bq,
    const float* __restrict__ Wk, const float* __restrict__ bk,
    const float* __restrict__ Wv, const float* __restrict__ bv,
    ushort_t* __restrict__ qb, ushort_t* __restrict__ kb,
    ushort_t* __restrict__ vT)
{
    __shared__ float xs[C_CH][64];        // 32 KB
    __shared__ float ws[3][I_CH][C_CH];   // 24 KB

    const int blk = blockIdx.x;
    const int b   = blk / (NVOX / 64);
    const int n0  = (blk % (NVOX / 64)) * 64;
    const int t   = threadIdx.x;

    {
        float4* wsq = (float4*)&ws[0][0][0];
        float4* wsk = (float4*)&ws[1][0][0];
        float4* wsv = (float4*)&ws[2][0][0];
        wsq[t]       = ((const float4*)Wq)[t];
        wsq[t + 256] = ((const float4*)Wq)[t + 256];
        wsk[t]       = ((const float4*)Wk)[t];
        wsk[t + 256] = ((const float4*)Wk)[t + 256];
        wsv[t]       = ((const float4*)Wv)[t];
        wsv[t + 256] = ((const float4*)Wv)[t + 256];
    }

    const float* xb = x + (size_t)b * C_CH * NVOX;
    #pragma unroll
    for (int rep = 0; rep < 8; ++rep) {
        int idx4 = rep * 256 + t;
        int c    = idx4 >> 4;
        int n4   = (idx4 & 15) << 2;
        *(float4*)&xs[c][n4] = *(const float4*)(xb + (size_t)c * NVOX + n0 + n4);
    }
    __syncthreads();

    const int n  = t & 63;
    const int iw = t >> 6;   // 0..3
    const int i0 = iw * 4;

    float aq[4] = {0.f,0.f,0.f,0.f};
    float ak[4] = {0.f,0.f,0.f,0.f};
    float av[4] = {0.f,0.f,0.f,0.f};

    #pragma unroll 2
    for (int c = 0; c < C_CH; c += 4) {
        float xv0 = xs[c + 0][n];
        float xv1 = xs[c + 1][n];
        float xv2 = xs[c + 2][n];
        float xv3 = xs[c + 3][n];
        #pragma unroll
        for (int j = 0; j < 4; ++j) {
            float4 w4;
            w4 = *(const float4*)&ws[0][i0 + j][c];
            aq[j] = fmaf(w4.x, xv0, fmaf(w4.y, xv1, fmaf(w4.z, xv2, fmaf(w4.w, xv3, aq[j]))));
            w4 = *(const float4*)&ws[1][i0 + j][c];
            ak[j] = fmaf(w4.x, xv0, fmaf(w4.y, xv1, fmaf(w4.z, xv2, fmaf(w4.w, xv3, ak[j]))));
            w4 = *(const float4*)&ws[2][i0 + j][c];
            av[j] = fmaf(w4.x, xv0, fmaf(w4.y, xv1, fmaf(w4.z, xv2, fmaf(w4.w, xv3, av[j]))));
        }
    }

    const size_t vox = (size_t)b * NVOX + n0 + n;
    ushort4 qv, kv;
    qv.x = f2bf_rne((aq[0] + bq[i0+0]) * LOG2E);
    qv.y = f2bf_rne((aq[1] + bq[i0+1]) * LOG2E);
    qv.z = f2bf_rne((aq[2] + bq[i0+2]) * LOG2E);
    qv.w = f2bf_rne((aq[3] + bq[i0+3]) * LOG2E);
    kv.x = f2bf_rne(ak[0] + bk[i0+0]); kv.y = f2bf_rne(ak[1] + bk[i0+1]);
    kv.z = f2bf_rne(ak[2] + bk[i0+2]); kv.w = f2bf_rne(ak[3] + bk[i0+3]);
    *(ushort4*)(qb + vox * I_CH + i0) = qv;
    *(ushort4*)(kb + vox * I_CH + i0) = kv;

    const int nl = n0 + n;
    #pragma unroll
    for (int j = 0; j < 4; ++j)
        vT[((size_t)b * I_CH + i0 + j) * NVOX + nl] = f2bf_rne(av[j] + bv[i0+j]);
}

// ---------------------------------------------------------------------------
// Kernel 2: fused MFMA flash attention + combine + output projection + resid.
// Block = 512 threads = 8 waves, 32 queries/block (576 blocks, 2.25 blk/CU).
// Wave w covers keys [w*1152, (w+1)*1152) in 18 iterations of 64 keys:
// two independent 32-key streams per iteration (ILP to fill the
// score-MFMA -> exp2 -> pack -> PV-MFMA dependency chain). Per stream:
// 4 score MFMA, 16 exp2, 8 packs, 2 PV MFMA, 2 l-MFMA (A=ones).
// Epilogue: LDS reduce, /l, Wo projection, residual. LDS padded <=2-way;
// NO dynamic register indexing (round-4's scratch-spill bug).
// ---------------------------------------------------------------------------
__global__ __launch_bounds__(512) void attn_kernel(
    const ushort_t* __restrict__ qb, const ushort_t* __restrict__ kb,
    const ushort_t* __restrict__ vT,
    const float* __restrict__ Wo, const float* __restrict__ bo,
    const float* __restrict__ gamma, const float* __restrict__ x,
    float* __restrict__ out)
{
    __shared__ float po[4][32][18];     // partial O; stride 18 -> <=2-way
    __shared__ float lsh[8][33];        // per-wave l (32 q), stride 33
    __shared__ float aot[16][40];       // ao[i][q], stride 40 (16B rows)
    __shared__ float wo_s[C_CH][17];    // Wo, stride 17 -> conflict-free

    const int tid  = threadIdx.x;
    const int w    = tid >> 6;
    const int lane = tid & 63;
    const int l16  = lane & 15;
    const int quad = lane >> 4;

    // stage Wo: thread -> (c = tid>>2, i0 = (tid&3)*4), coalesced float4 read
    {
        const int c  = tid >> 2;
        const int i4 = (tid & 3) * 4;
        float4 wv = *(const float4*)(Wo + c * I_CH + i4);
        wo_s[c][i4 + 0] = wv.x; wo_s[c][i4 + 1] = wv.y;
        wo_s[c][i4 + 2] = wv.z; wo_s[c][i4 + 3] = wv.w;
    }

    const int qvox0 = blockIdx.x * 32;
    const int b     = qvox0 / NVOX;
    const int nloc0 = qvox0 - b * NVOX;

    // Q B-frags (B[k=i][n=q], k = quad*8+j; zero for i>=16)
    bf16x8 qf0 = (bf16x8)0, qf1 = (bf16x8)0;
    if (quad < 2) {
        qf0 = __builtin_bit_cast(bf16x8,
              *(const int4*)(qb + (size_t)(qvox0 + l16) * I_CH + quad * 8));
        qf1 = __builtin_bit_cast(bf16x8,
              *(const int4*)(qb + (size_t)(qvox0 + 16 + l16) * I_CH + quad * 8));
    }

    // key permutation: score-row r -> key (r>>2)*8 + (r&3)  [+4 for tile1]
    const int p0     = ((l16 >> 2) << 3) + (l16 & 3);
    const int mchunk = w * (NVOX / 8);          // 1152 keys per wave
    const ushort_t* kp = kb + ((size_t)b * NVOX + mchunk + p0) * I_CH + (quad & 1) * 8;
    const ushort_t* vp = vT + ((size_t)b * I_CH + l16) * NVOX + mchunk + quad * 8;

    f32x4 O0 = {0.f,0.f,0.f,0.f}, O1 = {0.f,0.f,0.f,0.f};
    f32x4 L0 = {0.f,0.f,0.f,0.f}, L1 = {0.f,0.f,0.f,0.f};
    const f32x4 Z = {0.f,0.f,0.f,0.f};
    int4 onesi; onesi.x = onesi.y = onesi.z = onesi.w = 0x3F803F80;  // bf16 1.0
    const bf16x8 ones = __builtin_bit_cast(bf16x8, onesi);

    for (int it = 0; it < NVOX / 8 / 64; ++it) {
        // issue all loads for both 32-key streams up front
        int4 ka0a = *(const int4*)(kp);
        int4 ka1a = *(const int4*)(kp + 4 * I_CH);
        int4 vaa  = *(const int4*)(vp);
        int4 ka0b = *(const int4*)(kp + 32 * I_CH);
        int4 ka1b = *(const int4*)(kp + 36 * I_CH);
        int4 vab  = *(const int4*)(vp + 32);
        kp += 64 * I_CH;
        vp += 64;

        // ---- stream A (keys m .. m+31) ----
        f32x4 s00 = __builtin_amdgcn_mfma_f32_16x16x32_bf16(
            __builtin_bit_cast(bf16x8, ka0a), qf0, Z, 0, 0, 0);
        f32x4 s01 = __builtin_amdgcn_mfma_f32_16x16x32_bf16(
            __builtin_bit_cast(bf16x8, ka1a), qf0, Z, 0, 0, 0);
        f32x4 s10 = __builtin_amdgcn_mfma_f32_16x16x32_bf16(
            __builtin_bit_cast(bf16x8, ka0a), qf1, Z, 0, 0, 0);
        f32x4 s11 = __builtin_amdgcn_mfma_f32_16x16x32_bf16(
            __builtin_bit_cast(bf16x8, ka1a), qf1, Z, 0, 0, 0);

        // ---- stream B (keys m+32 .. m+63) ----
        f32x4 t00 = __builtin_amdgcn_mfma_f32_16x16x32_bf16(
            __builtin_bit_cast(bf16x8, ka0b), qf0, Z, 0, 0, 0);
        f32x4 t01 = __builtin_amdgcn_mfma_f32_16x16x32_bf16(
            __builtin_bit_cast(bf16x8, ka1b), qf0, Z, 0, 0, 0);
        f32x4 t10 = __builtin_amdgcn_mfma_f32_16x16x32_bf16(
            __builtin_bit_cast(bf16x8, ka0b), qf1, Z, 0, 0, 0);
        f32x4 t11 = __builtin_amdgcn_mfma_f32_16x16x32_bf16(
            __builtin_bit_cast(bf16x8, ka1b), qf1, Z, 0, 0, 0);

        // stream A, qtile 0
        {
            float p00 = fast_exp2(s00.x), p01 = fast_exp2(s00.y);
            float p02 = fast_exp2(s00.z), p03 = fast_exp2(s00.w);
            float p10 = fast_exp2(s01.x), p11 = fast_exp2(s01.y);
            float p12 = fast_exp2(s01.z), p13 = fast_exp2(s01.w);
            uint_t d0 = __builtin_amdgcn_perm(__builtin_bit_cast(uint_t, p01),
                                              __builtin_bit_cast(uint_t, p00), 0x07060302u);
            uint_t d1 = __builtin_amdgcn_perm(__builtin_bit_cast(uint_t, p03),
                                              __builtin_bit_cast(uint_t, p02), 0x07060302u);
            uint_t d2 = __builtin_amdgcn_perm(__builtin_bit_cast(uint_t, p11),
                                              __builtin_bit_cast(uint_t, p10), 0x07060302u);
            uint_t d3 = __builtin_amdgcn_perm(__builtin_bit_cast(uint_t, p13),
                                              __builtin_bit_cast(uint_t, p12), 0x07060302u);
            int4 pbi = make_int4((int)d0, (int)d1, (int)d2, (int)d3);
            bf16x8 pb = __builtin_bit_cast(bf16x8, pbi);
            O0 = __builtin_amdgcn_mfma_f32_16x16x32_bf16(
                __builtin_bit_cast(bf16x8, vaa), pb, O0, 0, 0, 0);
            L0 = __builtin_amdgcn_mfma_f32_16x16x32_bf16(ones, pb, L0, 0, 0, 0);
        }
        // stream A, qtile 1
        {
            float p00 = fast_exp2(s10.x), p01 = fast_exp2(s10.y);
            float p02 = fast_exp2(s10.z), p03 = fast_exp2(s10.w);
            float p10 = fast_exp2(s11.x), p11 = fast_exp2(s11.y);
            float p12 = fast_exp2(s11.z), p13 = fast_exp2(s11.w);
            uint_t d0 = __builtin_amdgcn_perm(__builtin_bit_cast(uint_t, p01),
                                              __builtin_bit_cast(uint_t, p00), 0x07060302u);
            uint_t d1 = __builtin_amdgcn_perm(__builtin_bit_cast(uint_t, p03),
                                              __builtin_bit_cast(uint_t, p02), 0x07060302u);
            uint_t d2 = __builtin_amdgcn_perm(__builtin_bit_cast(uint_t, p11),
                                              __builtin_bit_cast(uint_t, p10), 0x07060302u);
            uint_t d3 = __builtin_amdgcn_perm(__builtin_bit_cast(uint_t, p13),
                                              __builtin_bit_cast(uint_t, p12), 0x07060302u);
            int4 pbi = make_int4((int)d0, (int)d1, (int)d2, (int)d3);
            bf16x8 pb = __builtin_bit_cast(bf16x8, pbi);
            O1 = __builtin_amdgcn_mfma_f32_16x16x32_bf16(
                __builtin_bit_cast(bf16x8, vaa), pb, O1, 0, 0, 0);
            L1 = __builtin_amdgcn_mfma_f32_16x16x32_bf16(ones, pb, L1, 0, 0, 0);
        }
        // stream B, qtile 0
        {
            float p00 = fast_exp2(t00.x), p01 = fast_exp2(t00.y);
            float p02 = fast_exp2(t00.z), p03 = fast_exp2(t00.w);
            float p10 = fast_exp2(t01.x), p11 = fast_exp2(t01.y);
            float p12 = fast_exp2(t01.z), p13 = fast_exp2(t01.w);
            uint_t d0 = __builtin_amdgcn_perm(__builtin_bit_cast(uint_t, p01),
                                              __builtin_bit_cast(uint_t, p00), 0x07060302u);
            uint_t d1 = __builtin_amdgcn_perm(__builtin_bit_cast(uint_t, p03),
                                              __builtin_bit_cast(uint_t, p02), 0x07060302u);
            uint_t d2 = __builtin_amdgcn_perm(__builtin_bit_cast(uint_t, p11),
                                              __builtin_bit_cast(uint_t, p10), 0x07060302u);
            uint_t d3 = __builtin_amdgcn_perm(__builtin_bit_cast(uint_t, p13),
                                              __builtin_bit_cast(uint_t, p12), 0x07060302u);
            int4 pbi = make_int4((int)d0, (int)d1, (int)d2, (int)d3);
            bf16x8 pb = __builtin_bit_cast(bf16x8, pbi);
            O0 = __builtin_amdgcn_mfma_f32_16x16x32_bf16(
                __builtin_bit_cast(bf16x8, vab), pb, O0, 0, 0, 0);
            L0 = __builtin_amdgcn_mfma_f32_16x16x32_bf16(ones, pb, L0, 0, 0, 0);
        }
        // stream B, qtile 1
        {
            float p00 = fast_exp2(t10.x), p01 = fast_exp2(t10.y);
            float p02 = fast_exp2(t10.z), p03 = fast_exp2(t10.w);
            float p10 = fast_exp2(t11.x), p11 = fast_exp2(t11.y);
            float p12 = fast_exp2(t11.z), p13 = fast_exp2(t11.w);
            uint_t d0 = __builtin_amdgcn_perm(__builtin_bit_cast(uint_t, p01),
                                              __builtin_bit_cast(uint_t, p00), 0x07060302u);
            uint_t d1 = __builtin_amdgcn_perm(__builtin_bit_cast(uint_t, p03),
                                              __builtin_bit_cast(uint_t, p02), 0x07060302u);
            uint_t d2 = __builtin_amdgcn_perm(__builtin_bit_cast(uint_t, p11),
                                              __builtin_bit_cast(uint_t, p10), 0x07060302u);
            uint_t d3 = __builtin_amdgcn_perm(__builtin_bit_cast(uint_t, p13),
                                              __builtin_bit_cast(uint_t, p12), 0x07060302u);
            int4 pbi = make_int4((int)d0, (int)d1, (int)d2, (int)d3);
            bf16x8 pb = __builtin_bit_cast(bf16x8, pbi);
            O1 = __builtin_amdgcn_mfma_f32_16x16x32_bf16(
                __builtin_bit_cast(bf16x8, vab), pb, O1, 0, 0, 0);
            L1 = __builtin_amdgcn_mfma_f32_16x16x32_bf16(ones, pb, L1, 0, 0, 0);
        }
    }

    // ---- stage A: waves 0-3 deposit O; every wave deposits l ----
    if (w < 4) {
        #pragma unroll
        for (int r = 0; r < 4; ++r) {
            po[w][quad * 4 + r][l16]      = O0[r];   // qtile0: rows 0..15
            po[w][16 + quad * 4 + r][l16] = O1[r];   // qtile1: rows 16..31
        }
    }
    if (quad == 0) { lsh[w][l16] = L0.x; lsh[w][16 + l16] = L1.x; }
    __syncthreads();

    // ---- stage B: waves 4-7 accumulate into slot w-4 ----
    if (w >= 4) {
        #pragma unroll
        for (int r = 0; r < 4; ++r) {
            po[w - 4][quad * 4 + r][l16]      += O0[r];
            po[w - 4][16 + quad * 4 + r][l16] += O1[r];
        }
    }
    __syncthreads();

    // ---- combine: 512 threads -> aot[i][q] = (sum O)/(sum l) ----
    {
        const int q32 = tid & 31;
        const int i   = tid >> 5;           // 0..15
        const int row = (q32 >> 4) * 16 + i;
        const int col = q32 & 15;
        float v = 0.f, l = 0.f;
        #pragma unroll
        for (int ww = 0; ww < 4; ++ww) v += po[ww][row][col];
        #pragma unroll
        for (int ww = 0; ww < 8; ++ww) l += lsh[ww][q32];
        aot[i][q32] = v / l;
    }
    __syncthreads();

    // ---- projection + residual: thread -> (c = tid>>2, 8 queries) ----
    const float g  = gamma[0];
    const int   c  = tid >> 2;          // 0..127
    const int   qh = (tid & 3) * 8;     // 0,8,16,24

    float acc[8];
    {
        const float b0 = bo[c];
        #pragma unroll
        for (int q = 0; q < 8; ++q) acc[q] = b0;
    }
    #pragma unroll
    for (int i = 0; i < 16; ++i) {
        const float wv = wo_s[c][i];
        float4 a0 = *(const float4*)&aot[i][qh];
        float4 a1 = *(const float4*)&aot[i][qh + 4];
        acc[0] = fmaf(wv, a0.x, acc[0]); acc[1] = fmaf(wv, a0.y, acc[1]);
        acc[2] = fmaf(wv, a0.z, acc[2]); acc[3] = fmaf(wv, a0.w, acc[3]);
        acc[4] = fmaf(wv, a1.x, acc[4]); acc[5] = fmaf(wv, a1.y, acc[5]);
        acc[6] = fmaf(wv, a1.z, acc[6]); acc[7] = fmaf(wv, a1.w, acc[7]);
    }

    const size_t gi = ((size_t)b * C_CH + c) * NVOX + nloc0 + qh;
    float4 x0 = *(const float4*)(x + gi);
    float4 x1 = *(const float4*)(x + gi + 4);
    float4 o0, o1;
    o0.x = fmaf(g, acc[0], x0.x); o0.y = fmaf(g, acc[1], x0.y);
    o0.z = fmaf(g, acc[2], x0.z); o0.w = fmaf(g, acc[3], x0.w);
    o1.x = fmaf(g, acc[4], x1.x); o1.y = fmaf(g, acc[5], x1.y);
    o1.z = fmaf(g, acc[6], x1.z); o1.w = fmaf(g, acc[7], x1.w);
    *(float4*)(out + gi)     = o0;
    *(float4*)(out + gi + 4) = o1;
}

// ---------------------------------------------------------------------------
extern "C" void kernel_launch(void* const* d_in, const int* in_sizes, int n_in,
                              void* d_out, int out_size, void* d_ws, size_t ws_size,
                              hipStream_t stream) {
    const float* x     = (const float*)d_in[0];
    const float* Wq    = (const float*)d_in[1];
    const float* bq    = (const float*)d_in[2];
    const float* Wk    = (const float*)d_in[3];
    const float* bk    = (const float*)d_in[4];
    const float* Wv    = (const float*)d_in[5];
    const float* bv    = (const float*)d_in[6];
    const float* Wo    = (const float*)d_in[7];
    const float* bo    = (const float*)d_in[8];
    const float* gamma = (const float*)d_in[9];
    float* out = (float*)d_out;

    ushort_t* qb = (ushort_t*)d_ws;
    ushort_t* kb = qb + (size_t)BATCH * NVOX * I_CH;
    ushort_t* vT = kb + (size_t)BATCH * NVOX * I_CH;

    hipLaunchKernelGGL(qkv_kernel, dim3(BATCH * NVOX / 64), dim3(256), 0, stream,
                       x, Wq, bq, Wk, bk, Wv, bv, qb, kb, vT);
    hipLaunchKernelGGL(attn_kernel, dim3(BATCH * NVOX / 32), dim3(512), 0, stream,
                       qb, kb, vT, Wo, bo, gamma, x, out);
}

// Round 7
// 128.997 us; speedup vs baseline: 1.0081x; 1.0081x over previous
//
#include <hip/hip_runtime.h>

#define C_CH 128
#define I_CH 16
#define NVOX 9216   // 16*24*24
#define BATCH 2
#define LOG2E 1.44269504088896340736f

typedef unsigned short ushort_t;
typedef unsigned int uint_t;
typedef short bf16x8 __attribute__((ext_vector_type(8)));
typedef float f32x4 __attribute__((ext_vector_type(4)));

static __device__ inline ushort_t f2bf_rne(float x) {
    uint_t u = __builtin_bit_cast(uint_t, x);
    u = (u + 0x7FFFu + ((u >> 16) & 1u)) >> 16;
    return (ushort_t)u;
}

static __device__ inline float fast_exp2(float x) {
#if __has_builtin(__builtin_amdgcn_exp2f)
    return __builtin_amdgcn_exp2f(x);
#else
    return exp2f(x);
#endif
}

// ---------------------------------------------------------------------------
// Kernel 1: QKV projection -> bf16 (q pre-scaled by log2e).
// TLP-first design: 1152 blocks x 256 threads (4.5 waves/SIMD, ~33KB LDS
// -> 4 blocks/CU). Thread = (voxel n in 16, output i in 16); 3 accumulators
// (q,k,v) over 128 channels. W in padded LDS [16][132] (b128 reads, 4
// distinct i per wave -> 16 banks, conflict-free); xs[128][16] (16 distinct
// addrs/wave, conflict-free).
// ---------------------------------------------------------------------------
__global__ __launch_bounds__(256) void qkv_kernel(
    const float* __restrict__ x,
    const float* __restrict__ Wq, const float* __restrict__ bq,
    const float* __restrict__ Wk, const float* __restrict__ bk,
    const float* __restrict__ Wv, const float* __restrict__ bv,
    ushort_t* __restrict__ qb, ushort_t* __restrict__ kb,
    ushort_t* __restrict__ vT)
{
    __shared__ float ws[3][I_CH][132];   // padded stride 132 -> conflict-free
    __shared__ float xs[C_CH][I_CH];     // 8 KB

    const int t    = threadIdx.x;
    const int vox0 = blockIdx.x * 16;
    const int b    = vox0 / NVOX;
    const int n0   = vox0 - b * NVOX;

    // stage W: each thread 8 floats per matrix (2 float4), pad-aware
    {
        const int i  = t >> 4;           // 0..15
        const int c8 = (t & 15) * 8;     // 0..120
        const float4* wq4 = (const float4*)(Wq + i * C_CH + c8);
        const float4* wk4 = (const float4*)(Wk + i * C_CH + c8);
        const float4* wv4 = (const float4*)(Wv + i * C_CH + c8);
        *(float4*)&ws[0][i][c8]     = wq4[0];
        *(float4*)&ws[0][i][c8 + 4] = wq4[1];
        *(float4*)&ws[1][i][c8]     = wk4[0];
        *(float4*)&ws[1][i][c8 + 4] = wk4[1];
        *(float4*)&ws[2][i][c8]     = wv4[0];
        *(float4*)&ws[2][i][c8 + 4] = wv4[1];
    }

    // stage x tile: 128 ch x 16 vox = 2048 floats; thread -> (c, 4 cols), x2
    {
        const float* xb = x + (size_t)b * C_CH * NVOX + n0;
        const int c   = t >> 2;          // 0..63
        const int col = (t & 3) * 4;
        *(float4*)&xs[c][col]      = *(const float4*)(xb + (size_t)c * NVOX + col);
        *(float4*)&xs[c + 64][col] = *(const float4*)(xb + (size_t)(c + 64) * NVOX + col);
    }
    __syncthreads();

    const int n = t & 15;
    const int i = t >> 4;

    float aq = 0.f, ak = 0.f, av = 0.f;
    #pragma unroll 4
    for (int c = 0; c < C_CH; c += 4) {
        float x0 = xs[c + 0][n];
        float x1 = xs[c + 1][n];
        float x2 = xs[c + 2][n];
        float x3 = xs[c + 3][n];
        float4 wq = *(const float4*)&ws[0][i][c];
        float4 wk = *(const float4*)&ws[1][i][c];
        float4 wv = *(const float4*)&ws[2][i][c];
        aq = fmaf(wq.x, x0, fmaf(wq.y, x1, fmaf(wq.z, x2, fmaf(wq.w, x3, aq))));
        ak = fmaf(wk.x, x0, fmaf(wk.y, x1, fmaf(wk.z, x2, fmaf(wk.w, x3, ak))));
        av = fmaf(wv.x, x0, fmaf(wv.y, x1, fmaf(wv.z, x2, fmaf(wv.w, x3, av))));
    }

    const size_t vox = (size_t)vox0 + n;
    qb[vox * I_CH + i] = f2bf_rne((aq + bq[i]) * LOG2E);
    kb[vox * I_CH + i] = f2bf_rne(ak + bk[i]);
    vT[((size_t)b * I_CH + i) * NVOX + n0 + n] = f2bf_rne(av + bv[i]);
}

// ---------------------------------------------------------------------------
// Kernel 2: fused MFMA flash attention + combine + output projection + resid.
// Block = 1024 threads = 16 waves, 32 queries/block (576 blocks ->
// 2 blocks/CU resident, ~100% occupancy cap). Wave w covers keys
// [w*576, (w+1)*576) in 9 iterations of 64 keys (two independent 32-key
// streams -> ILP). Per-block K/V L2 traffic is independent of the wave
// split, so traffic is unchanged vs 8-wave version. Epilogue: 16->8->1
// LDS reduce, /l, Wo projection, residual. LDS padded <=2-way; NO dynamic
// register indexing (round-4's scratch-spill bug).
// ---------------------------------------------------------------------------
__global__ __launch_bounds__(1024) void attn_kernel(
    const ushort_t* __restrict__ qb, const ushort_t* __restrict__ kb,
    const ushort_t* __restrict__ vT,
    const float* __restrict__ Wo, const float* __restrict__ bo,
    const float* __restrict__ gamma, const float* __restrict__ x,
    float* __restrict__ out)
{
    __shared__ float po[8][32][18];     // partial O; stride 18 -> <=2-way
    __shared__ float lsh[16][33];       // per-wave l (32 q), stride 33
    __shared__ float aot[16][40];       // ao[i][q], stride 40 (16B rows)
    __shared__ float wo_s[C_CH][17];    // Wo, stride 17 -> conflict-free

    const int tid  = threadIdx.x;
    const int w    = tid >> 6;          // 0..15
    const int lane = tid & 63;
    const int l16  = lane & 15;
    const int quad = lane >> 4;

    // stage Wo (512 threads): thread -> (c = tid>>2, i0 = (tid&3)*4)
    if (tid < 512) {
        const int c  = tid >> 2;
        const int i4 = (tid & 3) * 4;
        float4 wv = *(const float4*)(Wo + c * I_CH + i4);
        wo_s[c][i4 + 0] = wv.x; wo_s[c][i4 + 1] = wv.y;
        wo_s[c][i4 + 2] = wv.z; wo_s[c][i4 + 3] = wv.w;
    }

    const int qvox0 = blockIdx.x * 32;
    const int b     = qvox0 / NVOX;
    const int nloc0 = qvox0 - b * NVOX;

    // Q B-frags (B[k=i][n=q], k = quad*8+j; zero for i>=16)
    bf16x8 qf0 = (bf16x8)0, qf1 = (bf16x8)0;
    if (quad < 2) {
        qf0 = __builtin_bit_cast(bf16x8,
              *(const int4*)(qb + (size_t)(qvox0 + l16) * I_CH + quad * 8));
        qf1 = __builtin_bit_cast(bf16x8,
              *(const int4*)(qb + (size_t)(qvox0 + 16 + l16) * I_CH + quad * 8));
    }

    // key permutation: score-row r -> key (r>>2)*8 + (r&3)  [+4 for tile1]
    const int p0     = ((l16 >> 2) << 3) + (l16 & 3);
    const int mchunk = w * (NVOX / 16);         // 576 keys per wave
    const ushort_t* kp = kb + ((size_t)b * NVOX + mchunk + p0) * I_CH + (quad & 1) * 8;
    const ushort_t* vp = vT + ((size_t)b * I_CH + l16) * NVOX + mchunk + quad * 8;

    f32x4 O0 = {0.f,0.f,0.f,0.f}, O1 = {0.f,0.f,0.f,0.f};
    f32x4 L0 = {0.f,0.f,0.f,0.f}, L1 = {0.f,0.f,0.f,0.f};
    const f32x4 Z = {0.f,0.f,0.f,0.f};
    int4 onesi; onesi.x = onesi.y = onesi.z = onesi.w = 0x3F803F80;  // bf16 1.0
    const bf16x8 ones = __builtin_bit_cast(bf16x8, onesi);

    for (int it = 0; it < NVOX / 16 / 64; ++it) {
        // issue all loads for both 32-key streams up front
        int4 ka0a = *(const int4*)(kp);
        int4 ka1a = *(const int4*)(kp + 4 * I_CH);
        int4 vaa  = *(const int4*)(vp);
        int4 ka0b = *(const int4*)(kp + 32 * I_CH);
        int4 ka1b = *(const int4*)(kp + 36 * I_CH);
        int4 vab  = *(const int4*)(vp + 32);
        kp += 64 * I_CH;
        vp += 64;

        // ---- stream A scores ----
        f32x4 s00 = __builtin_amdgcn_mfma_f32_16x16x32_bf16(
            __builtin_bit_cast(bf16x8, ka0a), qf0, Z, 0, 0, 0);
        f32x4 s01 = __builtin_amdgcn_mfma_f32_16x16x32_bf16(
            __builtin_bit_cast(bf16x8, ka1a), qf0, Z, 0, 0, 0);
        f32x4 s10 = __builtin_amdgcn_mfma_f32_16x16x32_bf16(
            __builtin_bit_cast(bf16x8, ka0a), qf1, Z, 0, 0, 0);
        f32x4 s11 = __builtin_amdgcn_mfma_f32_16x16x32_bf16(
            __builtin_bit_cast(bf16x8, ka1a), qf1, Z, 0, 0, 0);
        // ---- stream B scores ----
        f32x4 t00 = __builtin_amdgcn_mfma_f32_16x16x32_bf16(
            __builtin_bit_cast(bf16x8, ka0b), qf0, Z, 0, 0, 0);
        f32x4 t01 = __builtin_amdgcn_mfma_f32_16x16x32_bf16(
            __builtin_bit_cast(bf16x8, ka1b), qf0, Z, 0, 0, 0);
        f32x4 t10 = __builtin_amdgcn_mfma_f32_16x16x32_bf16(
            __builtin_bit_cast(bf16x8, ka0b), qf1, Z, 0, 0, 0);
        f32x4 t11 = __builtin_amdgcn_mfma_f32_16x16x32_bf16(
            __builtin_bit_cast(bf16x8, ka1b), qf1, Z, 0, 0, 0);

        // stream A, qtile 0
        {
            float p00 = fast_exp2(s00.x), p01 = fast_exp2(s00.y);
            float p02 = fast_exp2(s00.z), p03 = fast_exp2(s00.w);
            float p10 = fast_exp2(s01.x), p11 = fast_exp2(s01.y);
            float p12 = fast_exp2(s01.z), p13 = fast_exp2(s01.w);
            uint_t d0 = __builtin_amdgcn_perm(__builtin_bit_cast(uint_t, p01),
                                              __builtin_bit_cast(uint_t, p00), 0x07060302u);
            uint_t d1 = __builtin_amdgcn_perm(__builtin_bit_cast(uint_t, p03),
                                              __builtin_bit_cast(uint_t, p02), 0x07060302u);
            uint_t d2 = __builtin_amdgcn_perm(__builtin_bit_cast(uint_t, p11),
                                              __builtin_bit_cast(uint_t, p10), 0x07060302u);
            uint_t d3 = __builtin_amdgcn_perm(__builtin_bit_cast(uint_t, p13),
                                              __builtin_bit_cast(uint_t, p12), 0x07060302u);
            int4 pbi = make_int4((int)d0, (int)d1, (int)d2, (int)d3);
            bf16x8 pb = __builtin_bit_cast(bf16x8, pbi);
            O0 = __builtin_amdgcn_mfma_f32_16x16x32_bf16(
                __builtin_bit_cast(bf16x8, vaa), pb, O0, 0, 0, 0);
            L0 = __builtin_amdgcn_mfma_f32_16x16x32_bf16(ones, pb, L0, 0, 0, 0);
        }
        // stream A, qtile 1
        {
            float p00 = fast_exp2(s10.x), p01 = fast_exp2(s10.y);
            float p02 = fast_exp2(s10.z), p03 = fast_exp2(s10.w);
            float p10 = fast_exp2(s11.x), p11 = fast_exp2(s11.y);
            float p12 = fast_exp2(s11.z), p13 = fast_exp2(s11.w);
            uint_t d0 = __builtin_amdgcn_perm(__builtin_bit_cast(uint_t, p01),
                                              __builtin_bit_cast(uint_t, p00), 0x07060302u);
            uint_t d1 = __builtin_amdgcn_perm(__builtin_bit_cast(uint_t, p03),
                                              __builtin_bit_cast(uint_t, p02), 0x07060302u);
            uint_t d2 = __builtin_amdgcn_perm(__builtin_bit_cast(uint_t, p11),
                                              __builtin_bit_cast(uint_t, p10), 0x07060302u);
            uint_t d3 = __builtin_amdgcn_perm(__builtin_bit_cast(uint_t, p13),
                                              __builtin_bit_cast(uint_t, p12), 0x07060302u);
            int4 pbi = make_int4((int)d0, (int)d1, (int)d2, (int)d3);
            bf16x8 pb = __builtin_bit_cast(bf16x8, pbi);
            O1 = __builtin_amdgcn_mfma_f32_16x16x32_bf16(
                __builtin_bit_cast(bf16x8, vaa), pb, O1, 0, 0, 0);
            L1 = __builtin_amdgcn_mfma_f32_16x16x32_bf16(ones, pb, L1, 0, 0, 0);
        }
        // stream B, qtile 0
        {
            float p00 = fast_exp2(t00.x), p01 = fast_exp2(t00.y);
            float p02 = fast_exp2(t00.z), p03 = fast_exp2(t00.w);
            float p10 = fast_exp2(t01.x), p11 = fast_exp2(t01.y);
            float p12 = fast_exp2(t01.z), p13 = fast_exp2(t01.w);
            uint_t d0 = __builtin_amdgcn_perm(__builtin_bit_cast(uint_t, p01),
                                              __builtin_bit_cast(uint_t, p00), 0x07060302u);
            uint_t d1 = __builtin_amdgcn_perm(__builtin_bit_cast(uint_t, p03),
                                              __builtin_bit_cast(uint_t, p02), 0x07060302u);
            uint_t d2 = __builtin_amdgcn_perm(__builtin_bit_cast(uint_t, p11),
                                              __builtin_bit_cast(uint_t, p10), 0x07060302u);
            uint_t d3 = __builtin_amdgcn_perm(__builtin_bit_cast(uint_t, p13),
                                              __builtin_bit_cast(uint_t, p12), 0x07060302u);
            int4 pbi = make_int4((int)d0, (int)d1, (int)d2, (int)d3);
            bf16x8 pb = __builtin_bit_cast(bf16x8, pbi);
            O0 = __builtin_amdgcn_mfma_f32_16x16x32_bf16(
                __builtin_bit_cast(bf16x8, vab), pb, O0, 0, 0, 0);
            L0 = __builtin_amdgcn_mfma_f32_16x16x32_bf16(ones, pb, L0, 0, 0, 0);
        }
        // stream B, qtile 1
        {
            float p00 = fast_exp2(t10.x), p01 = fast_exp2(t10.y);
            float p02 = fast_exp2(t10.z), p03 = fast_exp2(t10.w);
            float p10 = fast_exp2(t11.x), p11 = fast_exp2(t11.y);
            float p12 = fast_exp2(t11.z), p13 = fast_exp2(t11.w);
            uint_t d0 = __builtin_amdgcn_perm(__builtin_bit_cast(uint_t, p01),
                                              __builtin_bit_cast(uint_t, p00), 0x07060302u);
            uint_t d1 = __builtin_amdgcn_perm(__builtin_bit_cast(uint_t, p03),
                                              __builtin_bit_cast(uint_t, p02), 0x07060302u);
            uint_t d2 = __builtin_amdgcn_perm(__builtin_bit_cast(uint_t, p11),
                                              __builtin_bit_cast(uint_t, p10), 0x07060302u);
            uint_t d3 = __builtin_amdgcn_perm(__builtin_bit_cast(uint_t, p13),
                                              __builtin_bit_cast(uint_t, p12), 0x07060302u);
            int4 pbi = make_int4((int)d0, (int)d1, (int)d2, (int)d3);
            bf16x8 pb = __builtin_bit_cast(bf16x8, pbi);
            O1 = __builtin_amdgcn_mfma_f32_16x16x32_bf16(
                __builtin_bit_cast(bf16x8, vab), pb, O1, 0, 0, 0);
            L1 = __builtin_amdgcn_mfma_f32_16x16x32_bf16(ones, pb, L1, 0, 0, 0);
        }
    }

    // ---- stage A: waves 0-7 deposit O; every wave deposits l ----
    if (w < 8) {
        #pragma unroll
        for (int r = 0; r < 4; ++r) {
            po[w][quad * 4 + r][l16]      = O0[r];   // qtile0: rows 0..15
            po[w][16 + quad * 4 + r][l16] = O1[r];   // qtile1: rows 16..31
        }
    }
    if (quad == 0) { lsh[w][l16] = L0.x; lsh[w][16 + l16] = L1.x; }
    __syncthreads();

    // ---- stage B: waves 8-15 accumulate into slot w-8 ----
    if (w >= 8) {
        #pragma unroll
        for (int r = 0; r < 4; ++r) {
            po[w - 8][quad * 4 + r][l16]      += O0[r];
            po[w - 8][16 + quad * 4 + r][l16] += O1[r];
        }
    }
    __syncthreads();

    // ---- combine: 512 threads -> aot[i][q] = (sum O)/(sum l) ----
    if (tid < 512) {
        const int q32 = tid & 31;
        const int i   = tid >> 5;           // 0..15
        const int row = (q32 >> 4) * 16 + i;
        const int col = q32 & 15;
        float v = 0.f, l = 0.f;
        #pragma unroll
        for (int ww = 0; ww < 8; ++ww) v += po[ww][row][col];
        #pragma unroll
        for (int ww = 0; ww < 16; ++ww) l += lsh[ww][q32];
        aot[i][q32] = v / l;
    }
    __syncthreads();

    // ---- projection + residual: thread -> (c = tid>>3, 4 queries) ----
    const float g  = gamma[0];
    const int   c  = tid >> 3;          // 0..127
    const int   q4 = (tid & 7) * 4;     // 0,4,...,28

    float4 acc;
    acc.x = acc.y = acc.z = acc.w = bo[c];
    #pragma unroll
    for (int i = 0; i < 16; ++i) {
        const float wv = wo_s[c][i];
        float4 a = *(const float4*)&aot[i][q4];
        acc.x = fmaf(wv, a.x, acc.x); acc.y = fmaf(wv, a.y, acc.y);
        acc.z = fmaf(wv, a.z, acc.z); acc.w = fmaf(wv, a.w, acc.w);
    }

    const size_t gi = ((size_t)b * C_CH + c) * NVOX + nloc0 + q4;
    float4 xv = *(const float4*)(x + gi);
    float4 ov;
    ov.x = fmaf(g, acc.x, xv.x); ov.y = fmaf(g, acc.y, xv.y);
    ov.z = fmaf(g, acc.z, xv.z); ov.w = fmaf(g, acc.w, xv.w);
    *(float4*)(out + gi) = ov;
}

// ---------------------------------------------------------------------------
extern "C" void kernel_launch(void* const* d_in, const int* in_sizes, int n_in,
                              void* d_out, int out_size, void* d_ws, size_t ws_size,
                              hipStream_t stream) {
    const float* x     = (const float*)d_in[0];
    const float* Wq    = (const float*)d_in[1];
    const float* bq    = (const float*)d_in[2];
    const float* Wk    = (const float*)d_in[3];
    const float* bk    = (const float*)d_in[4];
    const float* Wv    = (const float*)d_in[5];
    const float* bv    = (const float*)d_in[6];
    const float* Wo    = (const float*)d_in[7];
    const float* bo    = (const float*)d_in[8];
    const float* gamma = (const float*)d_in[9];
    float* out = (float*)d_out;

    ushort_t* qb = (ushort_t*)d_ws;
    ushort_t* kb = qb + (size_t)BATCH * NVOX * I_CH;
    ushort_t* vT = kb + (size_t)BATCH * NVOX * I_CH;

    hipLaunchKernelGGL(qkv_kernel, dim3(BATCH * NVOX / 16), dim3(256), 0, stream,
                       x, Wq, bq, Wk, bk, Wv, bv, qb, kb, vT);
    hipLaunchKernelGGL(attn_kernel, dim3(BATCH * NVOX / 32), dim3(1024), 0, stream,
                       qb, kb, vT, Wo, bo, gamma, x, out);
}